// Round 4
// baseline (64.424 us; speedup 1.0000x reference)
//
#include <hip/hip_runtime.h>
#include <math.h>

#define MLEN 4096
#define LOG2M 12
#define RANK 8
#define NSAMP 2048

__device__ __forceinline__ float softplus_f(float x) {
    return (x > 20.0f) ? x : log1pf(expf(x));
}

// ---------------------------------------------------------------------------
// Kernel 1: full complex FFT of softplus(H) rows -> Hft in d_ws (256 KB).
// In-place iterative DIT (bit-reversed load), single 32 KB LDS buffer.
// One block per row (R = 8 blocks). Real input => full M-point FFT equals
// reference's concat([Hf[:, :Nf], conj(flip(Hf[:, 1:Nf-1]))]) exactly.
// ---------------------------------------------------------------------------
__global__ __launch_bounds__(256) void fft_rows_kernel(const float* __restrict__ H,
                                                       float2* __restrict__ Hft) {
    __shared__ float2 buf[MLEN];            // 32 KB
    const int d = blockIdx.x;
    const float* row = H + d * MLEN;

    for (int i = threadIdx.x; i < MLEN; i += 256) {
        int src = (int)(__brev((unsigned)i) >> (32 - LOG2M));
        buf[i] = make_float2(softplus_f(row[src]), 0.0f);
    }
    __syncthreads();

    for (int s = 1; s <= LOG2M; ++s) {
        const int len  = 1 << s;
        const int half = len >> 1;
        for (int p = threadIdx.x; p < (MLEN >> 1); p += 256) {
            const int k  = p & (half - 1);
            const int j  = p >> (s - 1);
            const int i0 = j * len + k;
            const int i1 = i0 + half;
            float sw, cw;                    // w = exp(-2*pi*i*k/len)
            sincospif(-2.0f * (float)k / (float)len, &sw, &cw);
            float2 a = buf[i0];
            float2 b = buf[i1];
            float tr = b.x * cw - b.y * sw;
            float ti = b.x * sw + b.y * cw;
            buf[i0] = make_float2(a.x + tr, a.y + ti);
            buf[i1] = make_float2(a.x - tr, a.y - ti);
        }
        __syncthreads();
    }

    float2* outrow = Hft + d * MLEN;
    for (int i = threadIdx.x; i < MLEN; i += 256) outrow[i] = buf[i];
}

// ---------------------------------------------------------------------------
// Kernel 2: V[n,m] = sum_d softplus(W[n,d]) * exp(-2pi*i*tau[n,d]*m/M) * Hft[d,m]
// REAL_ONLY=1: write Re(V) as float (harness cast complex ref to float32).
// REAL_ONLY=0: write interleaved complex64 layout (float2).
// ---------------------------------------------------------------------------
template <int REAL_ONLY>
__global__ __launch_bounds__(256) void mix_kernel(const float* __restrict__ W,
                                                  const float* __restrict__ tau,
                                                  const float2* __restrict__ Hft,
                                                  float* __restrict__ out) {
    const int n = blockIdx.y;
    const int m = blockIdx.x * 256 + threadIdx.x;

    __shared__ float spw[RANK];
    __shared__ float tl[RANK];
    if (threadIdx.x < RANK) {
        spw[threadIdx.x] = softplus_f(W[n * RANK + threadIdx.x]);
        tl[threadIdx.x]  = tau[n * RANK + threadIdx.x];
    }
    __syncthreads();

    const float fm = (float)m * (1.0f / (float)MLEN);
    float ar = 0.0f, ai = 0.0f;
#pragma unroll
    for (int d = 0; d < RANK; ++d) {
        const float ang = -6.28318530717958647692f * (tl[d] * fm);  // radians
        const float c = __cosf(ang);
        const float s = __sinf(ang);
        const float2 h = Hft[d * MLEN + m];
        const float cs = spw[d] * c;
        const float ss = spw[d] * s;
        ar += cs * h.x - ss * h.y;
        ai += cs * h.y + ss * h.x;
    }
    if (REAL_ONLY) {
        out[(size_t)n * MLEN + m] = ar;
    } else {
        ((float2*)out)[(size_t)n * MLEN + m] = make_float2(ar, ai);
    }
}

extern "C" void kernel_launch(void* const* d_in, const int* in_sizes, int n_in,
                              void* d_out, int out_size, void* d_ws, size_t ws_size,
                              hipStream_t stream) {
    const float* W   = (const float*)d_in[0];   // (N, R)
    const float* H   = (const float*)d_in[1];   // (R, M)
    const float* tau = (const float*)d_in[2];   // (N, R)
    float2* Hft = (float2*)d_ws;                // (R, M) complex, 256 KB scratch
    float* out  = (float*)d_out;

    fft_rows_kernel<<<RANK, 256, 0, stream>>>(H, Hft);

    const long long NM = (long long)NSAMP * MLEN;
    if ((long long)out_size >= 2 * NM) {
        // complex64 interleaved layout (float32 view, 2*N*M elements)
        mix_kernel<0><<<dim3(MLEN / 256, NSAMP), 256, 0, stream>>>(W, tau, Hft, out);
    } else {
        // harness stored real part only (N*M float32 elements)
        mix_kernel<1><<<dim3(MLEN / 256, NSAMP), 256, 0, stream>>>(W, tau, Hft, out);
    }
}

// Round 5
// 43.858 us; speedup vs baseline: 1.4689x; 1.4689x over previous
//
#include <hip/hip_runtime.h>
#include <math.h>

#define MLEN 4096
#define LOG2M 12
#define RANK 8
#define NSAMP 2048
#define VEC 8      // m-points per thread (strided by 256)
#define NS  2      // samples (n) per thread, reusing Hft loads

__device__ __forceinline__ float softplus_f(float x) {
    return (x > 20.0f) ? x : log1pf(expf(x));
}

// ---------------------------------------------------------------------------
// Kernel 1: full complex FFT of softplus(H) rows -> Hft in d_ws (256 KB).
// In-place iterative DIT (bit-reversed load), single 32 KB LDS buffer.
// One block per row (R = 8 blocks). Native __sincosf twiddles (|ang| < 2*pi).
// ---------------------------------------------------------------------------
__global__ __launch_bounds__(256) void fft_rows_kernel(const float* __restrict__ H,
                                                       float2* __restrict__ Hft) {
    __shared__ float2 buf[MLEN];            // 32 KB
    const int d = blockIdx.x;
    const float* row = H + d * MLEN;

    for (int i = threadIdx.x; i < MLEN; i += 256) {
        int src = (int)(__brev((unsigned)i) >> (32 - LOG2M));
        buf[i] = make_float2(softplus_f(row[src]), 0.0f);
    }
    __syncthreads();

    for (int s = 1; s <= LOG2M; ++s) {
        const int len  = 1 << s;
        const int half = len >> 1;
        for (int p = threadIdx.x; p < (MLEN >> 1); p += 256) {
            const int k  = p & (half - 1);
            const int j  = p >> (s - 1);
            const int i0 = j * len + k;
            const int i1 = i0 + half;
            float sw, cw;                    // w = exp(-2*pi*i*k/len)
            __sincosf(-6.28318530717958647692f * (float)k / (float)len, &sw, &cw);
            float2 a = buf[i0];
            float2 b = buf[i1];
            float tr = b.x * cw - b.y * sw;
            float ti = b.x * sw + b.y * cw;
            buf[i0] = make_float2(a.x + tr, a.y + ti);
            buf[i1] = make_float2(a.x - tr, a.y - ti);
        }
        __syncthreads();
    }

    float2* outrow = Hft + d * MLEN;
    for (int i = threadIdx.x; i < MLEN; i += 256) outrow[i] = buf[i];
}

// ---------------------------------------------------------------------------
// Kernel 2: V[n,m] = sum_d softplus(W[n,d]) * exp(-i*2pi*tau[n,d]*m/M) * Hft[d,m]
// Phase-recurrence version: per (n,d) one __sincosf pair for the base phasor
// (pre-scaled by softplus(W)) + one for the unit step; then 4-FMA rotation per
// m-step. Each thread: VEC m-points (stride 256) x NS samples (Hft reuse).
// Grid: (MLEN/(256*VEC), NSAMP/NS) = (2, 1024) blocks of 256.
// ---------------------------------------------------------------------------
template <int REAL_ONLY>
__global__ __launch_bounds__(256) void mix_kernel(const float* __restrict__ W,
                                                  const float* __restrict__ tau,
                                                  const float2* __restrict__ Hft,
                                                  float* __restrict__ out) {
    const int tid = threadIdx.x;
    const int m0  = blockIdx.x * (256 * VEC) + tid;
    const int n0  = blockIdx.y * NS;

    __shared__ float s_spw[NS * RANK];
    __shared__ float s_tau[NS * RANK];
    if (tid < NS * RANK) {
        s_spw[tid] = softplus_f(W[n0 * RANK + tid]);   // rows n0..n0+NS-1 contiguous
        s_tau[tid] = tau[n0 * RANK + tid];
    }
    __syncthreads();

    float ar[NS][VEC];
    float ai[NS][VEC];   // dead (DCE) in REAL_ONLY instantiation
#pragma unroll
    for (int j = 0; j < NS; ++j)
#pragma unroll
        for (int k = 0; k < VEC; ++k) { ar[j][k] = 0.0f; ai[j][k] = 0.0f; }

    const float th0f = -6.28318530717958647692f * ((float)m0 * (1.0f / (float)MLEN));
    const float dthf = -6.28318530717958647692f * (256.0f / (float)MLEN);

#pragma unroll
    for (int d = 0; d < RANK; ++d) {
        float cs[NS], sn[NS], dc[NS], ds[NS];
#pragma unroll
        for (int j = 0; j < NS; ++j) {
            const float t   = s_tau[j * RANK + d];
            const float spw = s_spw[j * RANK + d];
            float c0, s0;
            __sincosf(th0f * t, &s0, &c0);             // |ang| <= 2*pi*5 (proven ok R4)
            __sincosf(dthf * t, &ds[j], &dc[j]);       // unit step rotation
            cs[j] = spw * c0;                          // phasor pre-scaled by spw
            sn[j] = spw * s0;
        }
        const float2* __restrict__ hrow = Hft + d * MLEN + m0;
#pragma unroll
        for (int k = 0; k < VEC; ++k) {
            const float2 h = hrow[k * 256];
#pragma unroll
            for (int j = 0; j < NS; ++j) {
                ar[j][k] += cs[j] * h.x - sn[j] * h.y;        // Re(spw*e^{i th}*h)
                if (!REAL_ONLY) ai[j][k] += cs[j] * h.y + sn[j] * h.x;
                const float ncs = cs[j] * dc[j] - sn[j] * ds[j];
                sn[j] = cs[j] * ds[j] + sn[j] * dc[j];
                cs[j] = ncs;
            }
        }
    }

#pragma unroll
    for (int j = 0; j < NS; ++j) {
#pragma unroll
        for (int k = 0; k < VEC; ++k) {
            const size_t idx = (size_t)(n0 + j) * MLEN + m0 + k * 256;
            if (REAL_ONLY) out[idx] = ar[j][k];
            else ((float2*)out)[idx] = make_float2(ar[j][k], ai[j][k]);
        }
    }
}

extern "C" void kernel_launch(void* const* d_in, const int* in_sizes, int n_in,
                              void* d_out, int out_size, void* d_ws, size_t ws_size,
                              hipStream_t stream) {
    const float* W   = (const float*)d_in[0];   // (N, R)
    const float* H   = (const float*)d_in[1];   // (R, M)
    const float* tau = (const float*)d_in[2];   // (N, R)
    float2* Hft = (float2*)d_ws;                // (R, M) complex, 256 KB scratch
    float* out  = (float*)d_out;

    fft_rows_kernel<<<RANK, 256, 0, stream>>>(H, Hft);

    const long long NM = (long long)NSAMP * MLEN;
    dim3 grid(MLEN / (256 * VEC), NSAMP / NS);
    if ((long long)out_size >= 2 * NM) {
        mix_kernel<0><<<grid, 256, 0, stream>>>(W, tau, Hft, out);
    } else {
        mix_kernel<1><<<grid, 256, 0, stream>>>(W, tau, Hft, out);
    }
}

// Round 6
// 36.211 us; speedup vs baseline: 1.7791x; 1.2112x over previous
//
#include <hip/hip_runtime.h>
#include <math.h>

#define MLEN 4096
#define LOG2M 12
#define RANK 8
#define NSAMP 2048
#define VEC 16     // m-points per thread (strided by 256)
#define NS  2      // samples (n) per thread, reusing Hft loads

__device__ __forceinline__ float softplus_f(float x) {
    return (x > 20.0f) ? x : log1pf(expf(x));
}

// ---------------------------------------------------------------------------
// Kernel 1: full complex FFT of softplus(H) rows -> Hft in d_ws (256 KB).
// In-place iterative DIT (bit-reversed load), 32 KB LDS, 1024 threads/block
// (16 waves = 4/SIMD for LDS latency hiding). One block per row (8 blocks).
// ---------------------------------------------------------------------------
__global__ __launch_bounds__(1024) void fft_rows_kernel(const float* __restrict__ H,
                                                        float2* __restrict__ Hft) {
    __shared__ float2 buf[MLEN];            // 32 KB
    const int d = blockIdx.x;
    const float* row = H + d * MLEN;

    for (int i = threadIdx.x; i < MLEN; i += 1024) {
        int src = (int)(__brev((unsigned)i) >> (32 - LOG2M));
        buf[i] = make_float2(softplus_f(row[src]), 0.0f);
    }
    __syncthreads();

    for (int s = 1; s <= LOG2M; ++s) {
        const int half = 1 << (s - 1);
#pragma unroll 2
        for (int p = threadIdx.x; p < (MLEN >> 1); p += 1024) {
            const int k  = p & (half - 1);
            const int i0 = ((p >> (s - 1)) << s) + k;
            const int i1 = i0 + half;
            float sw, cw;                    // w = exp(-2*pi*i*k/len)
            __sincosf(-6.28318530717958647692f * (float)k / (float)(half << 1), &sw, &cw);
            float2 a = buf[i0];
            float2 b = buf[i1];
            float tr = b.x * cw - b.y * sw;
            float ti = b.x * sw + b.y * cw;
            buf[i0] = make_float2(a.x + tr, a.y + ti);
            buf[i1] = make_float2(a.x - tr, a.y - ti);
        }
        __syncthreads();
    }

    float2* outrow = Hft + d * MLEN;
    for (int i = threadIdx.x; i < MLEN; i += 1024) outrow[i] = buf[i];
}

// ---------------------------------------------------------------------------
// Kernel 2: V[n,m] = sum_d softplus(W[n,d]) * exp(-i*2pi*tau[n,d]*m/M) * Hft[d,m]
// Phase recurrence: one __sincosf pair per (n,d) for base phasor (pre-scaled
// by softplus(W)) + one for the step; 4-FMA rotation per m-step thereafter.
// Each thread: VEC=16 m-points (stride 256) x NS=2 samples (Hft reuse).
// Grid: (MLEN/(256*VEC), NSAMP/NS) = (1, 1024) blocks of 256.
// ---------------------------------------------------------------------------
template <int REAL_ONLY>
__global__ __launch_bounds__(256) void mix_kernel(const float* __restrict__ W,
                                                  const float* __restrict__ tau,
                                                  const float2* __restrict__ Hft,
                                                  float* __restrict__ out) {
    const int tid = threadIdx.x;
    const int m0  = blockIdx.x * (256 * VEC) + tid;
    const int n0  = blockIdx.y * NS;

    __shared__ float s_spw[NS * RANK];
    __shared__ float s_tau[NS * RANK];
    if (tid < NS * RANK) {
        s_spw[tid] = softplus_f(W[n0 * RANK + tid]);
        s_tau[tid] = tau[n0 * RANK + tid];
    }
    __syncthreads();

    float ar[NS][VEC];
    float ai[NS][VEC];   // dead (DCE) in REAL_ONLY instantiation
#pragma unroll
    for (int j = 0; j < NS; ++j)
#pragma unroll
        for (int k = 0; k < VEC; ++k) { ar[j][k] = 0.0f; ai[j][k] = 0.0f; }

    const float th0f = -6.28318530717958647692f * ((float)m0 * (1.0f / (float)MLEN));
    const float dthf = -6.28318530717958647692f * (256.0f / (float)MLEN);

#pragma unroll
    for (int d = 0; d < RANK; ++d) {
        float cs[NS], sn[NS], dc[NS], ds[NS];
#pragma unroll
        for (int j = 0; j < NS; ++j) {
            const float t   = s_tau[j * RANK + d];
            const float spw = s_spw[j * RANK + d];
            float c0, s0;
            __sincosf(th0f * t, &s0, &c0);
            __sincosf(dthf * t, &ds[j], &dc[j]);
            cs[j] = spw * c0;
            sn[j] = spw * s0;
        }
        // batch the 16 rank-d loads for deep load pipelining
        const float2* __restrict__ hrow = Hft + d * MLEN + m0;
        float2 hv[VEC];
#pragma unroll
        for (int k = 0; k < VEC; ++k) hv[k] = hrow[k * 256];
#pragma unroll
        for (int k = 0; k < VEC; ++k) {
#pragma unroll
            for (int j = 0; j < NS; ++j) {
                ar[j][k] += cs[j] * hv[k].x - sn[j] * hv[k].y;
                if (!REAL_ONLY) ai[j][k] += cs[j] * hv[k].y + sn[j] * hv[k].x;
                const float ncs = cs[j] * dc[j] - sn[j] * ds[j];
                sn[j] = cs[j] * ds[j] + sn[j] * dc[j];
                cs[j] = ncs;
            }
        }
    }

#pragma unroll
    for (int j = 0; j < NS; ++j) {
#pragma unroll
        for (int k = 0; k < VEC; ++k) {
            const size_t idx = (size_t)(n0 + j) * MLEN + m0 + k * 256;
            if (REAL_ONLY) out[idx] = ar[j][k];
            else ((float2*)out)[idx] = make_float2(ar[j][k], ai[j][k]);
        }
    }
}

extern "C" void kernel_launch(void* const* d_in, const int* in_sizes, int n_in,
                              void* d_out, int out_size, void* d_ws, size_t ws_size,
                              hipStream_t stream) {
    const float* W   = (const float*)d_in[0];   // (N, R)
    const float* H   = (const float*)d_in[1];   // (R, M)
    const float* tau = (const float*)d_in[2];   // (N, R)
    float2* Hft = (float2*)d_ws;                // (R, M) complex, 256 KB scratch
    float* out  = (float*)d_out;

    fft_rows_kernel<<<RANK, 1024, 0, stream>>>(H, Hft);

    const long long NM = (long long)NSAMP * MLEN;
    dim3 grid(MLEN / (256 * VEC), NSAMP / NS);
    if ((long long)out_size >= 2 * NM) {
        mix_kernel<0><<<grid, 256, 0, stream>>>(W, tau, Hft, out);
    } else {
        mix_kernel<1><<<grid, 256, 0, stream>>>(W, tau, Hft, out);
    }
}

// Round 7
// 33.146 us; speedup vs baseline: 1.9436x; 1.0925x over previous
//
#include <hip/hip_runtime.h>
#include <math.h>

#define MLEN 4096
#define LOG2M 12
#define RANK 8
#define NSAMP 2048
#define VEC 8      // m-points per thread (strided by 256)
#define NS  4      // samples (n) per thread, reusing Hft loads

__device__ __forceinline__ float softplus_f(float x) {
    return (x > 20.0f) ? x : log1pf(expf(x));
}

// ---------------------------------------------------------------------------
// Kernel 1: full complex FFT of softplus(H) rows -> Hft in d_ws (256 KB).
// In-place iterative DIT (bit-reversed load), 32 KB LDS, 1024 threads/block.
// One block per row (8 blocks). Pure __sinf/__cosf twiddles (no pointer
// outputs -> no scratch risk).
// ---------------------------------------------------------------------------
__global__ __launch_bounds__(1024) void fft_rows_kernel(const float* __restrict__ H,
                                                        float2* __restrict__ Hft) {
    __shared__ float2 buf[MLEN];            // 32 KB
    const int d = blockIdx.x;
    const float* row = H + d * MLEN;

    for (int i = threadIdx.x; i < MLEN; i += 1024) {
        int src = (int)(__brev((unsigned)i) >> (32 - LOG2M));
        buf[i] = make_float2(softplus_f(row[src]), 0.0f);
    }
    __syncthreads();

    for (int s = 1; s <= LOG2M; ++s) {
        const int half = 1 << (s - 1);
#pragma unroll 2
        for (int p = threadIdx.x; p < (MLEN >> 1); p += 1024) {
            const int k  = p & (half - 1);
            const int i0 = ((p >> (s - 1)) << s) + k;
            const int i1 = i0 + half;
            const float ang = -6.28318530717958647692f * (float)k / (float)(half << 1);
            const float sw = __sinf(ang);
            const float cw = __cosf(ang);
            float2 a = buf[i0];
            float2 b = buf[i1];
            float tr = b.x * cw - b.y * sw;
            float ti = b.x * sw + b.y * cw;
            buf[i0] = make_float2(a.x + tr, a.y + ti);
            buf[i1] = make_float2(a.x - tr, a.y - ti);
        }
        __syncthreads();
    }

    float2* outrow = Hft + d * MLEN;
    for (int i = threadIdx.x; i < MLEN; i += 1024) outrow[i] = buf[i];
}

// ---------------------------------------------------------------------------
// Kernel 2: V[n,m] = sum_d softplus(W[n,d]) * exp(-i*2pi*tau[n,d]*m/M) * Hft[d,m]
// Phase recurrence: per (n,d) one native sin/cos pair for the base phasor
// (pre-scaled by softplus(W)) + one for the step; 4-FMA rotation per m-step.
// Tiling: NS=4 samples x VEC=8 m-points per thread.
//   - 4 independent rotation chains/thread (latency hiding)
//   - Hft L2 reads / NS = 134 MB total
// Grid: (MLEN/(256*VEC), NSAMP/NS) = (2, 512) blocks of 256.
// ---------------------------------------------------------------------------
template <int REAL_ONLY>
__global__ __launch_bounds__(256) void mix_kernel(const float* __restrict__ W,
                                                  const float* __restrict__ tau,
                                                  const float2* __restrict__ Hft,
                                                  float* __restrict__ out) {
    const int tid = threadIdx.x;
    const int m0  = blockIdx.x * (256 * VEC) + tid;
    const int n0  = blockIdx.y * NS;

    __shared__ float s_spw[NS * RANK];
    __shared__ float s_tau[NS * RANK];
    if (tid < NS * RANK) {
        s_spw[tid] = softplus_f(W[n0 * RANK + tid]);
        s_tau[tid] = tau[n0 * RANK + tid];
    }
    __syncthreads();

    float ar[NS][VEC];
    float ai[NS][VEC];   // dead (DCE) in REAL_ONLY instantiation
#pragma unroll
    for (int j = 0; j < NS; ++j)
#pragma unroll
        for (int k = 0; k < VEC; ++k) { ar[j][k] = 0.0f; ai[j][k] = 0.0f; }

    const float th0f = -6.28318530717958647692f * ((float)m0 * (1.0f / (float)MLEN));
    const float dthf = -6.28318530717958647692f * (256.0f / (float)MLEN);

#pragma unroll
    for (int d = 0; d < RANK; ++d) {
        float cs[NS], sn[NS], dc[NS], ds[NS];
#pragma unroll
        for (int j = 0; j < NS; ++j) {
            const float t   = s_tau[j * RANK + d];
            const float spw = s_spw[j * RANK + d];
            const float a0 = th0f * t;
            const float a1 = dthf * t;
            const float c0 = __cosf(a0);
            const float s0 = __sinf(a0);
            dc[j] = __cosf(a1);
            ds[j] = __sinf(a1);
            cs[j] = spw * c0;             // phasor pre-scaled by softplus(W)
            sn[j] = spw * s0;
        }
        const float2* __restrict__ hrow = Hft + d * MLEN + m0;
        float2 hv[VEC];
#pragma unroll
        for (int k = 0; k < VEC; ++k) hv[k] = hrow[k * 256];
#pragma unroll
        for (int k = 0; k < VEC; ++k) {
#pragma unroll
            for (int j = 0; j < NS; ++j) {
                ar[j][k] += cs[j] * hv[k].x - sn[j] * hv[k].y;
                if (!REAL_ONLY) ai[j][k] += cs[j] * hv[k].y + sn[j] * hv[k].x;
                const float ncs = cs[j] * dc[j] - sn[j] * ds[j];
                sn[j] = cs[j] * ds[j] + sn[j] * dc[j];
                cs[j] = ncs;
            }
        }
    }

#pragma unroll
    for (int j = 0; j < NS; ++j) {
#pragma unroll
        for (int k = 0; k < VEC; ++k) {
            const size_t idx = (size_t)(n0 + j) * MLEN + m0 + k * 256;
            if (REAL_ONLY) out[idx] = ar[j][k];
            else ((float2*)out)[idx] = make_float2(ar[j][k], ai[j][k]);
        }
    }
}

extern "C" void kernel_launch(void* const* d_in, const int* in_sizes, int n_in,
                              void* d_out, int out_size, void* d_ws, size_t ws_size,
                              hipStream_t stream) {
    const float* W   = (const float*)d_in[0];   // (N, R)
    const float* H   = (const float*)d_in[1];   // (R, M)
    const float* tau = (const float*)d_in[2];   // (N, R)
    float2* Hft = (float2*)d_ws;                // (R, M) complex, 256 KB scratch
    float* out  = (float*)d_out;

    fft_rows_kernel<<<RANK, 1024, 0, stream>>>(H, Hft);

    const long long NM = (long long)NSAMP * MLEN;
    dim3 grid(MLEN / (256 * VEC), NSAMP / NS);
    if ((long long)out_size >= 2 * NM) {
        mix_kernel<0><<<grid, 256, 0, stream>>>(W, tau, Hft, out);
    } else {
        mix_kernel<1><<<grid, 256, 0, stream>>>(W, tau, Hft, out);
    }
}